// Round 1
// baseline (94.738 us; speedup 1.0000x reference)
//
#include <hip/hip_runtime.h>

// SpikeEncoder: temporal one-hot coding.
//   lat[b,s,n] = int32( ((1 - clamp(f,0,1)) * 20) * scale[n] )   (trunc toward 0)
//   out[b,s,t,n] = (lat[b,s,n] == t) ? 1.0f : 0.0f
// Shapes: features [8,128,1024] f32, scale [1024] f32, out [8,128,20,1024] f32.
//
// Write-bound: ~84 MB out vs 4 MB in. One thread per 4 neurons; 20 coalesced
// 16B stores per thread (t-stride = 4 KB; lane-contiguous in n => 1 KB/wave/instr).
//
// R1 change: NONTEMPORAL stores. The timed graph carries a 320 MiB dirty poison
// fill right before us; normal stores write-allocate into L2/L3 and churn
// against those dirty lines (~2.3 TB/s observed). `nt` stores bypass cache
// allocation and stream like the fill kernel itself (~6.5 TB/s observed).

#define N_TIMESTEPS 20
#define N_NEURONS   1024
#define BATCH       8
#define SEQ_LEN     128

typedef float __attribute__((ext_vector_type(4))) f32x4;

__global__ __launch_bounds__(256) void spike_encoder_kernel(
    const f32x4* __restrict__ feat,   // [B*S*N/4]
    const f32x4* __restrict__ scale,  // [N/4]
    f32x4* __restrict__ out)          // [B*S*T*N/4]
{
    const int idx = blockIdx.x * blockDim.x + threadIdx.x;  // over B*S*N/4
    const int n4  = idx & (N_NEURONS / 4 - 1);              // neuron-group index
    const int bs  = idx >> 8;                               // b*S + s  (N/4 == 256)

    const f32x4 f  = feat[idx];
    const f32x4 sc = scale[n4];

    // Match numpy fp32 rounding exactly: (1 - clamp(f)) round, *20 round,
    // *scale round, then trunc-toward-zero. __fsub_rn/__fmul_rn block FMA
    // contraction which could flip truncation at integer boundaries.
    const int lat_x = (int)__fmul_rn(__fmul_rn(__fsub_rn(1.0f, fminf(fmaxf(f.x, 0.0f), 1.0f)), 20.0f), sc.x);
    const int lat_y = (int)__fmul_rn(__fmul_rn(__fsub_rn(1.0f, fminf(fmaxf(f.y, 0.0f), 1.0f)), 20.0f), sc.y);
    const int lat_z = (int)__fmul_rn(__fmul_rn(__fsub_rn(1.0f, fminf(fmaxf(f.z, 0.0f), 1.0f)), 20.0f), sc.z);
    const int lat_w = (int)__fmul_rn(__fmul_rn(__fsub_rn(1.0f, fminf(fmaxf(f.w, 0.0f), 1.0f)), 20.0f), sc.w);

    // out[bs, t, n4]: base = bs * T * (N/4) + t * (N/4) + n4
    f32x4* p = out + (size_t)bs * (N_TIMESTEPS * (N_NEURONS / 4)) + n4;

#pragma unroll
    for (int t = 0; t < N_TIMESTEPS; ++t) {
        f32x4 v;
        v.x = (lat_x == t) ? 1.0f : 0.0f;
        v.y = (lat_y == t) ? 1.0f : 0.0f;
        v.z = (lat_z == t) ? 1.0f : 0.0f;
        v.w = (lat_w == t) ? 1.0f : 0.0f;
        __builtin_nontemporal_store(v, p + (size_t)t * (N_NEURONS / 4));
    }
}

extern "C" void kernel_launch(void* const* d_in, const int* in_sizes, int n_in,
                              void* d_out, int out_size, void* d_ws, size_t ws_size,
                              hipStream_t stream) {
    const f32x4* feat  = (const f32x4*)d_in[0];  // [B,S,N] f32
    const f32x4* scale = (const f32x4*)d_in[1];  // [N] f32
    f32x4* out = (f32x4*)d_out;                  // [B,S,T,N] f32

    const int total4 = BATCH * SEQ_LEN * N_NEURONS / 4;  // 262144
    const int block = 256;
    const int grid = total4 / block;                     // 1024
    spike_encoder_kernel<<<grid, block, 0, stream>>>(feat, scale, out);
}

// Round 2
// 89.036 us; speedup vs baseline: 1.0640x; 1.0640x over previous
//
#include <hip/hip_runtime.h>

// SpikeEncoder: temporal one-hot coding.
//   lat[b,s,n] = int32( ((1 - clamp(f,0,1)) * 20) * scale[n] )   (trunc toward 0)
//   out[b,s,t,n] = (lat[b,s,n] == t) ? 1.0f : 0.0f
// Shapes: features [8,128,1024] f32, scale [1024] f32, out [8,128,20,1024] f32.
//
// Write-bound: ~84 MB out vs 4 MB in.
//
// R2 change: fill-shaped store stream. The runtime's fillBuffer kernel hits
// 6.5 TB/s at 8.75% occupancy by having few waves each stream long SEQUENTIAL
// runs of dwordx4 stores. Mimic it: ONE WAVE per bs-slab (1024 waves, 4/CU).
// Each wave hoists its 4 feat loads + 4 scale loads (single vmcnt wait),
// computes 16 latencies, then writes its 80 KB output slab fully sequentially:
// 80 back-to-back 16B-per-lane stores at consecutive 1 KB wave-chunks.
// Same bytes, same exact fp32 rounding chain as the 88.5 µs baseline; shape only.

#define N_TIMESTEPS 20
#define N_NEURONS   1024
#define BATCH       8
#define SEQ_LEN     128

typedef float __attribute__((ext_vector_type(4))) f32x4;

__device__ __forceinline__ int lat_of(float f, float s) {
    // Match numpy fp32 rounding exactly: (1 - clamp(f)) round, *20 round,
    // *scale round, then trunc-toward-zero. __fsub_rn/__fmul_rn block FMA
    // contraction which could flip truncation at integer boundaries.
    return (int)__fmul_rn(__fmul_rn(__fsub_rn(1.0f, fminf(fmaxf(f, 0.0f), 1.0f)), 20.0f), s);
}

__global__ __launch_bounds__(256) void spike_encoder_kernel(
    const f32x4* __restrict__ feat,   // [B*S, N/4]
    const f32x4* __restrict__ scale,  // [N/4]
    f32x4* __restrict__ out)          // [B*S, T, N/4]
{
    const int lane = threadIdx.x & 63;
    const int wave = threadIdx.x >> 6;                 // 0..3
    const int bs   = blockIdx.x * 4 + wave;            // 0..1023 (one bs-slab per wave)

    // Hoist all loads: 4 feat vectors + 4 scale vectors per lane, one wait.
    const f32x4* fb = feat + bs * (N_NEURONS / 4);
    const f32x4 f0 = fb[0 * 64 + lane];
    const f32x4 f1 = fb[1 * 64 + lane];
    const f32x4 f2 = fb[2 * 64 + lane];
    const f32x4 f3 = fb[3 * 64 + lane];
    const f32x4 s0 = scale[0 * 64 + lane];
    const f32x4 s1 = scale[1 * 64 + lane];
    const f32x4 s2 = scale[2 * 64 + lane];
    const f32x4 s3 = scale[3 * 64 + lane];

    int lat[4][4];
    lat[0][0] = lat_of(f0.x, s0.x); lat[0][1] = lat_of(f0.y, s0.y);
    lat[0][2] = lat_of(f0.z, s0.z); lat[0][3] = lat_of(f0.w, s0.w);
    lat[1][0] = lat_of(f1.x, s1.x); lat[1][1] = lat_of(f1.y, s1.y);
    lat[1][2] = lat_of(f1.z, s1.z); lat[1][3] = lat_of(f1.w, s1.w);
    lat[2][0] = lat_of(f2.x, s2.x); lat[2][1] = lat_of(f2.y, s2.y);
    lat[2][2] = lat_of(f2.z, s2.z); lat[2][3] = lat_of(f2.w, s2.w);
    lat[3][0] = lat_of(f3.x, s3.x); lat[3][1] = lat_of(f3.y, s3.y);
    lat[3][2] = lat_of(f3.z, s3.z); lat[3][3] = lat_of(f3.w, s3.w);

    // Sequential 80 KB stream per wave: address order (t, c) ascending,
    // each instruction = 64 lanes x 16 B = 1 KB contiguous.
    f32x4* ob = out + (size_t)bs * (N_TIMESTEPS * (N_NEURONS / 4));

#pragma unroll
    for (int t = 0; t < N_TIMESTEPS; ++t) {
#pragma unroll
        for (int c = 0; c < 4; ++c) {
            f32x4 v;
            v.x = (lat[c][0] == t) ? 1.0f : 0.0f;
            v.y = (lat[c][1] == t) ? 1.0f : 0.0f;
            v.z = (lat[c][2] == t) ? 1.0f : 0.0f;
            v.w = (lat[c][3] == t) ? 1.0f : 0.0f;
            ob[t * (N_NEURONS / 4) + c * 64 + lane] = v;
        }
    }
}

extern "C" void kernel_launch(void* const* d_in, const int* in_sizes, int n_in,
                              void* d_out, int out_size, void* d_ws, size_t ws_size,
                              hipStream_t stream) {
    const f32x4* feat  = (const f32x4*)d_in[0];  // [B,S,N] f32
    const f32x4* scale = (const f32x4*)d_in[1];  // [N] f32
    f32x4* out = (f32x4*)d_out;                  // [B,S,T,N] f32

    const int grid = BATCH * SEQ_LEN / 4;        // 256 blocks x 4 waves = 1024 bs-slabs
    spike_encoder_kernel<<<grid, 256, 0, stream>>>(feat, scale, out);
}